// Round 1
// 559.179 us; speedup vs baseline: 1.0650x; 1.0650x over previous
//
#include <hip/hip_runtime.h>
#include <hip/hip_bf16.h>
#include <hip/hip_fp16.h>

typedef float f32x4 __attribute__((ext_vector_type(4)));
typedef short short8 __attribute__((ext_vector_type(8)));
typedef _Float16 h4 __attribute__((ext_vector_type(4)));
typedef unsigned short u16;
typedef unsigned int u32;

#define BK 32  // linear LDS k-stride (u16): 64B rows, XOR-swizzled 16B slots

__device__ __forceinline__ u16 bf16_rne(float x) {
  u32 u = __float_as_uint(x);
  u += 0x7FFFu + ((u >> 16) & 1u);
  return (u16)(u >> 16);
}
__device__ __forceinline__ u32 pack2(float a, float b) {
  return (u32)bf16_rne(a) | ((u32)bf16_rne(b) << 16);
}

// ---------------------------------------------------------------------------
// convert: fp32 -> bf16 RNE for x, ctx, Wq, Wk, Wv.  2048 elems/block.
// blocks: x[0,8192) ctx[8192,16384) wq[16384,16896) wk[..17408) wv[..17920)
// ---------------------------------------------------------------------------
__global__ __launch_bounds__(256)
void convert_kernel(const float* __restrict__ x, const float* __restrict__ ctx,
                    const float* __restrict__ wq, const float* __restrict__ wk,
                    const float* __restrict__ wv,
                    u16* __restrict__ xb, u16* __restrict__ cb,
                    u16* __restrict__ wqb, u16* __restrict__ wkb,
                    u16* __restrict__ wvb)
{
  int blk = blockIdx.x;
  const float* src; u16* dst; size_t off;
  if (blk < 8192)       { src = x;   dst = xb;  off = (size_t)blk * 2048; }
  else if (blk < 16384) { src = ctx; dst = cb;  off = (size_t)(blk - 8192) * 2048; }
  else if (blk < 16896) { src = wq;  dst = wqb; off = (size_t)(blk - 16384) * 2048; }
  else if (blk < 17408) { src = wk;  dst = wkb; off = (size_t)(blk - 16896) * 2048; }
  else                  { src = wv;  dst = wvb; off = (size_t)(blk - 17408) * 2048; }
  size_t e = off + (size_t)threadIdx.x * 8;
  float4 a = *(const float4*)(src + e);
  float4 b = *(const float4*)(src + e + 4);
  uint4 o;
  o.x = pack2(a.x, a.y); o.y = pack2(a.z, a.w);
  o.z = pack2(b.x, b.y); o.w = pack2(b.z, b.w);
  *(uint4*)(dst + e) = o;
}

// ---------------------------------------------------------------------------
// shared GEMM pieces: 128x128 tile, BK=32, 4 waves of 64x64, 16x16x32 bf16.
// Staging: global_load_lds width=16, linear LDS dest (wave base + lane*16).
// Bank-conflict fix: 16B-slot XOR swizzle, slot ^= (row>>1)&3, applied as
// inverse-swizzled GLOBAL source + swizzled ds_read (rule: both sides or
// neither; global_load_lds writes linearly).
// ---------------------------------------------------------------------------
__device__ __forceinline__ void stage_async(const u16* __restrict__ G, int ld,
                                            u16* L, int w, int lane)
{
  const int r_in = lane >> 2;                               // 0..15
  const int scol = ((lane & 3) ^ ((r_in >> 1) & 3)) * 8;    // pre-swizzled src slot
#pragma unroll
  for (int it = 0; it < 2; ++it) {
    const int rbase = w * 32 + it * 16;                     // wave-uniform
    const u16* g = G + (size_t)(rbase + r_in) * ld + scol;
    u16* l = L + rbase * BK;
    __builtin_amdgcn_global_load_lds(
        (const __attribute__((address_space(1))) void*)g,
        (__attribute__((address_space(3))) void*)l, 16, 0, 0);
  }
}

#define GEMM_FRAGS_AND_MFMA(Ah, Bh)                                            \
  short8 a_f[4], b_f[4];                                                       \
  _Pragma("unroll")                                                            \
  for (int i = 0; i < 4; ++i) {                                                \
    a_f[i] = *(const short8*)&Ah[(wm + i * 16 + lrow) * BK + sq8];             \
    b_f[i] = *(const short8*)&Bh[(wn + i * 16 + lrow) * BK + sq8];             \
  }                                                                            \
  _Pragma("unroll")                                                            \
  for (int i = 0; i < 4; ++i)                                                  \
    _Pragma("unroll")                                                          \
    for (int j = 0; j < 4; ++j)                                                \
      acc[i][j] = __builtin_amdgcn_mfma_f32_16x16x32_bf16(a_f[i], b_f[j], acc[i][j], 0, 0, 0);

#define GEMM_PROLOGUE                                                          \
  const int tid = threadIdx.x;                                                 \
  const int w = tid >> 6, lane = tid & 63;                                     \
  const int wm = (w >> 1) * 64, wn = (w & 1) * 64;                             \
  const int lrow = lane & 15, quad = lane >> 4;                                \
  const int sq8 = (quad ^ ((lrow >> 1) & 3)) * 8;                              \
  f32x4 acc[4][4];                                                             \
  _Pragma("unroll")                                                            \
  for (int i = 0; i < 4; ++i)                                                  \
    _Pragma("unroll")                                                          \
    for (int j = 0; j < 4; ++j) {                                              \
      f32x4 z = {0.f, 0.f, 0.f, 0.f};                                          \
      acc[i][j] = z;                                                           \
    }

// ---------------------------------------------------------------------------
// projq: Y[M,1024] bf16 = A[M,1024] @ W[1024,1024]^T + bias   (q and k)
// ---------------------------------------------------------------------------
__global__ __launch_bounds__(256)
void projq_kernel(const u16* __restrict__ A, const u16* __restrict__ W,
                  const float* __restrict__ bias, u16* __restrict__ Y)
{
  __shared__ __align__(16) u16 Ah[128 * BK];
  __shared__ __align__(16) u16 Bh[128 * BK];
  const int m0 = blockIdx.y * 128, n0 = blockIdx.x * 128;
  GEMM_PROLOGUE
  const u16* A_b = A + (size_t)m0 * 1024;
  const u16* B_b = W + (size_t)n0 * 1024;

  for (int kt = 0; kt < 1024; kt += 32) {
    __syncthreads();
    stage_async(A_b + kt, 1024, Ah, w, lane);
    stage_async(B_b + kt, 1024, Bh, w, lane);
    __syncthreads();
    GEMM_FRAGS_AND_MFMA(Ah, Bh)
  }

#pragma unroll
  for (int j = 0; j < 4; ++j) {
    int gn = n0 + wn + j * 16 + lrow;
    float bj = bias[gn];
#pragma unroll
    for (int i = 0; i < 4; ++i) {
      int gm_base = m0 + wm + i * 16 + quad * 4;
#pragma unroll
      for (int r = 0; r < 4; ++r)
        Y[(size_t)(gm_base + r) * 1024 + gn] = bf16_rne(acc[i][j][r] + bj);
    }
  }
}

// ---------------------------------------------------------------------------
// projv: Vt[b][e][t] bf16 = (ctx @ Wv^T + bv) transposed, via LDS bounce.
// ---------------------------------------------------------------------------
__global__ __launch_bounds__(256)
void projv_kernel(const u16* __restrict__ A, const u16* __restrict__ W,
                  const float* __restrict__ bias, u16* __restrict__ Vt)
{
  __shared__ __align__(16) u16 smem[128 * 136];  // 34816 B; staging uses first 16384 B
  u16* Ah = smem;
  u16* Bh = smem + 128 * BK;
  const int m0 = blockIdx.y * 128, n0 = blockIdx.x * 128;
  const int bb = m0 >> 11, t0 = m0 & 2047;
  GEMM_PROLOGUE
  const u16* A_b = A + (size_t)m0 * 1024;
  const u16* B_b = W + (size_t)n0 * 1024;

  for (int kt = 0; kt < 1024; kt += 32) {
    __syncthreads();
    stage_async(A_b + kt, 1024, Ah, w, lane);
    stage_async(B_b + kt, 1024, Bh, w, lane);
    __syncthreads();
    GEMM_FRAGS_AND_MFMA(Ah, Bh)
  }

  // transpose via LDS: T[e_local][t_local], stride 136 u16
  __syncthreads();
  u16* T = smem;
#pragma unroll
  for (int j = 0; j < 4; ++j) {
    int e_l = wn + j * 16 + lrow;
    float bj = bias[n0 + e_l];
#pragma unroll
    for (int i = 0; i < 4; ++i) {
      int t_l = wm + i * 16 + quad * 4;
      uint2 p;
      p.x = pack2(acc[i][j][0] + bj, acc[i][j][1] + bj);
      p.y = pack2(acc[i][j][2] + bj, acc[i][j][3] + bj);
      *(uint2*)&T[e_l * 136 + t_l] = p;
    }
  }
  __syncthreads();

  // coalesced write: 2 threads per e-row, 8 x 16B each
  int e_l = tid >> 1, half = tid & 1;
  u16* gdst = Vt + ((size_t)(bb * 1024 + n0 + e_l)) * 2048 + t0 + half * 64;
  const u16* Trow = &T[e_l * 136 + half * 64];
#pragma unroll
  for (int k = 0; k < 8; ++k)
    *(uint4*)(gdst + k * 8) = *(const uint4*)(Trow + k * 8);
}

// ---------------------------------------------------------------------------
// score: S[b,s,t] fp16 = scale * (q[b] @ k[b]^T)
// ---------------------------------------------------------------------------
__global__ __launch_bounds__(256)
void score_kernel(const u16* __restrict__ qb, const u16* __restrict__ kb,
                  _Float16* __restrict__ S)
{
  __shared__ __align__(16) u16 Ah[128 * BK];
  __shared__ __align__(16) u16 Bh[128 * BK];
  const int b = blockIdx.z;
  const int m0 = blockIdx.y * 128, n0 = blockIdx.x * 128;
  GEMM_PROLOGUE
  const u16* A_b = qb + ((size_t)b * 2048 + m0) * 1024;
  const u16* B_b = kb + ((size_t)b * 2048 + n0) * 1024;

  for (int kt = 0; kt < 1024; kt += 32) {
    __syncthreads();
    stage_async(A_b + kt, 1024, Ah, w, lane);
    stage_async(B_b + kt, 1024, Bh, w, lane);
    __syncthreads();
    GEMM_FRAGS_AND_MFMA(Ah, Bh)
  }

  const float scale = 0.03125f;  // 1/sqrt(1024)
#pragma unroll
  for (int j = 0; j < 4; ++j) {
    int gn = n0 + wn + j * 16 + lrow;
#pragma unroll
    for (int i = 0; i < 4; ++i) {
      int gm_base = m0 + wm + i * 16 + quad * 4;
#pragma unroll
      for (int r = 0; r < 4; ++r)
        S[((size_t)b * 2048 + gm_base + r) * 2048 + gn] = (_Float16)(acc[i][j][r] * scale);
    }
  }
}

// ---------------------------------------------------------------------------
// softmax over S rows (fp16 in), writes P bf16 in place (same 4096B row).
// ---------------------------------------------------------------------------
__global__ __launch_bounds__(256)
void softmax_kernel(_Float16* __restrict__ S)
{
  const int row = blockIdx.x;
  const int tid = threadIdx.x;
  _Float16* Sr = S + (size_t)row * 2048;
  h4 ah = *(const h4*)(Sr + tid * 4);
  h4 bh = *(const h4*)(Sr + 1024 + tid * 4);
  float a0 = (float)ah.x, a1 = (float)ah.y, a2 = (float)ah.z, a3 = (float)ah.w;
  float b0 = (float)bh.x, b1 = (float)bh.y, b2 = (float)bh.z, b3 = (float)bh.w;

  float m = fmaxf(fmaxf(fmaxf(a0, a1), fmaxf(a2, a3)),
                  fmaxf(fmaxf(b0, b1), fmaxf(b2, b3)));
#pragma unroll
  for (int off = 32; off > 0; off >>= 1) m = fmaxf(m, __shfl_xor(m, off));

  __shared__ float red[4];
  const int wid = tid >> 6, lane = tid & 63;
  if (lane == 0) red[wid] = m;
  __syncthreads();
  m = fmaxf(fmaxf(red[0], red[1]), fmaxf(red[2], red[3]));

  float e0 = __expf(a0 - m), e1 = __expf(a1 - m), e2 = __expf(a2 - m), e3 = __expf(a3 - m);
  float e4 = __expf(b0 - m), e5 = __expf(b1 - m), e6 = __expf(b2 - m), e7 = __expf(b3 - m);
  float s = ((e0 + e1) + (e2 + e3)) + ((e4 + e5) + (e6 + e7));
#pragma unroll
  for (int off = 32; off > 0; off >>= 1) s += __shfl_xor(s, off);
  __syncthreads();
  if (lane == 0) red[wid] = s;
  __syncthreads();
  s = red[0] + red[1] + red[2] + red[3];
  float inv = 1.0f / s;

  u16* P = (u16*)S;
  size_t pb = (size_t)row * 2048;
  uint2 w0, w1;
  w0.x = pack2(e0 * inv, e1 * inv);
  w0.y = pack2(e2 * inv, e3 * inv);
  w1.x = pack2(e4 * inv, e5 * inv);
  w1.y = pack2(e6 * inv, e7 * inv);
  *(uint2*)&P[pb + tid * 4] = w0;
  *(uint2*)&P[pb + 1024 + tid * 4] = w1;
}

// ---------------------------------------------------------------------------
// pv: O[b,s,e] fp32 = P[b] @ Vt[b]^T   (P row stride 2048, Vt row stride 2048)
// ---------------------------------------------------------------------------
__global__ __launch_bounds__(256)
void pv_kernel(const u16* __restrict__ P, const u16* __restrict__ Vt,
               float* __restrict__ O)
{
  __shared__ __align__(16) u16 Ah[128 * BK];
  __shared__ __align__(16) u16 Bh[128 * BK];
  const int b = blockIdx.z;
  const int m0 = blockIdx.y * 128, n0 = blockIdx.x * 128;
  GEMM_PROLOGUE
  const u16* A_b = P + ((size_t)b * 2048 + m0) * 2048;
  const u16* B_b = Vt + ((size_t)b * 1024 + n0) * 2048;

  for (int kt = 0; kt < 2048; kt += 32) {
    __syncthreads();
    stage_async(A_b + kt, 2048, Ah, w, lane);
    stage_async(B_b + kt, 2048, Bh, w, lane);
    __syncthreads();
    GEMM_FRAGS_AND_MFMA(Ah, Bh)
  }

#pragma unroll
  for (int j = 0; j < 4; ++j) {
    int gn = n0 + wn + j * 16 + lrow;
#pragma unroll
    for (int i = 0; i < 4; ++i) {
      int gm_base = m0 + wm + i * 16 + quad * 4;
#pragma unroll
      for (int r = 0; r < 4; ++r)
        O[((size_t)b * 2048 + gm_base + r) * 1024 + gn] = acc[i][j][r];
    }
  }
}

// ---------------------------------------------------------------------------
extern "C" void kernel_launch(void* const* d_in, const int* in_sizes, int n_in,
                              void* d_out, int out_size, void* d_ws, size_t ws_size,
                              hipStream_t stream) {
  const float* x   = (const float*)d_in[0];
  const float* ctx = (const float*)d_in[1];
  const float* Wq  = (const float*)d_in[2];
  const float* bq  = (const float*)d_in[3];
  const float* Wk  = (const float*)d_in[4];
  const float* bk  = (const float*)d_in[5];
  const float* Wv  = (const float*)d_in[6];
  const float* bv  = (const float*)d_in[7];
  float* out = (float*)d_out;

  // ws layout (u16 elems): [xb 16.8M][cb 16.8M][qb][kb][vt][wqb 1M][wkb][wvb]
  // S (fp16, 33.5M elems = 64 MiB) aliases [xb cb] (dead after proj).
  const size_t NQ = (size_t)16384 * 1024;   // 16.8M
  const size_t NW = (size_t)1024 * 1024;    // 1M
  const size_t needed = (5 * NQ + 3 * NW) * sizeof(u16);  // ~174 MiB
  if (ws_size < needed) return;

  u16* xb  = (u16*)d_ws;
  u16* cb  = xb + NQ;
  u16* qb  = cb + NQ;
  u16* kb  = qb + NQ;
  u16* vt  = kb + NQ;
  u16* wqb = vt + NQ;
  u16* wkb = wqb + NW;
  u16* wvb = wkb + NW;
  _Float16* S = (_Float16*)d_ws;  // aliases xb+cb after projections complete

  dim3 blk(256, 1, 1);
  hipLaunchKernelGGL(convert_kernel, dim3(17920, 1, 1), blk, 0, stream,
                     x, ctx, Wq, Wk, Wv, xb, cb, wqb, wkb, wvb);
  hipLaunchKernelGGL(projq_kernel, dim3(8, 128, 1), blk, 0, stream, xb, wqb, bq, qb);
  hipLaunchKernelGGL(projq_kernel, dim3(8, 128, 1), blk, 0, stream, cb, wkb, bk, kb);
  hipLaunchKernelGGL(projv_kernel, dim3(8, 128, 1), blk, 0, stream, cb, wvb, bv, vt);
  hipLaunchKernelGGL(score_kernel, dim3(16, 16, 8), blk, 0, stream, qb, kb, S);
  hipLaunchKernelGGL(softmax_kernel, dim3(16384, 1, 1), blk, 0, stream, S);
  hipLaunchKernelGGL(pv_kernel, dim3(8, 16, 8), blk, 0, stream, (const u16*)S, vt, out);
}

// Round 2
// 514.517 us; speedup vs baseline: 1.1575x; 1.0868x over previous
//
#include <hip/hip_runtime.h>
#include <hip/hip_bf16.h>
#include <hip/hip_fp16.h>

typedef float f32x4 __attribute__((ext_vector_type(4)));
typedef short short8 __attribute__((ext_vector_type(8)));
typedef _Float16 h4 __attribute__((ext_vector_type(4)));
typedef unsigned short u16;
typedef unsigned int u32;

__device__ __forceinline__ u16 bf16_rne(float x) {
  u32 u = __float_as_uint(x);
  u += 0x7FFFu + ((u >> 16) & 1u);
  return (u16)(u >> 16);
}
__device__ __forceinline__ u32 pack2(float a, float b) {
  return (u32)bf16_rne(a) | ((u32)bf16_rne(b) << 16);
}

// ---------------------------------------------------------------------------
// convert: fp32 -> bf16 RNE for x, ctx, Wq, Wk, Wv.  2048 elems/block.
// ---------------------------------------------------------------------------
__global__ __launch_bounds__(256)
void convert_kernel(const float* __restrict__ x, const float* __restrict__ ctx,
                    const float* __restrict__ wq, const float* __restrict__ wk,
                    const float* __restrict__ wv,
                    u16* __restrict__ xb, u16* __restrict__ cb,
                    u16* __restrict__ wqb, u16* __restrict__ wkb,
                    u16* __restrict__ wvb)
{
  int blk = blockIdx.x;
  const float* src; u16* dst; size_t off;
  if (blk < 8192)       { src = x;   dst = xb;  off = (size_t)blk * 2048; }
  else if (blk < 16384) { src = ctx; dst = cb;  off = (size_t)(blk - 8192) * 2048; }
  else if (blk < 16896) { src = wq;  dst = wqb; off = (size_t)(blk - 16384) * 2048; }
  else if (blk < 17408) { src = wk;  dst = wkb; off = (size_t)(blk - 16896) * 2048; }
  else                  { src = wv;  dst = wvb; off = (size_t)(blk - 17408) * 2048; }
  size_t e = off + (size_t)threadIdx.x * 8;
  float4 a = *(const float4*)(src + e);
  float4 b = *(const float4*)(src + e + 4);
  uint4 o;
  o.x = pack2(a.x, a.y); o.y = pack2(a.z, a.w);
  o.z = pack2(b.x, b.y); o.w = pack2(b.z, b.w);
  *(uint4*)(dst + e) = o;
}

// ---------------------------------------------------------------------------
// 256x256 tile, BK=64, 8 waves (2Mx4N), 8-phase schedule, counted vmcnt.
// LDS 128 KiB: buf p in [p*64K, +64K): A halves at +0/+16K, B at +32K/+48K.
// st_16x32 swizzle: byte ^= ((byte>>9)&1)<<5, applied on global source
// (global_load_lds writes linearly) and on ds_read offsets (involution).
// ---------------------------------------------------------------------------
#define BARRIER() __builtin_amdgcn_s_barrier()
#define LGKM0() do { asm volatile("s_waitcnt lgkmcnt(0)" ::: "memory"); \
                     __builtin_amdgcn_sched_barrier(0); } while (0)
#define VMCNT(n) asm volatile("s_waitcnt vmcnt(" #n ")" ::: "memory")

__device__ __forceinline__ void stage_half(const u16* __restrict__ Gt, int ld2,
                                           char* dst, int w, int lane)
{
  // half = 128 rows x 128 B. Per issue: 64 rows, wave w covers rows w*8..w*8+8.
  const int rsub = lane >> 3;                                   // 0..7
  const int cbx = ((lane & 7) * 16) ^ (((lane >> 5) & 1) << 5); // pre-swizzled col
#pragma unroll
  for (int it = 0; it < 2; ++it) {
    const char* g = (const char*)Gt + (size_t)(it * 64 + w * 8 + rsub) * ld2 + cbx;
    char* l = dst + it * 8192 + w * 1024;                       // wave-uniform
    __builtin_amdgcn_global_load_lds(
        (const __attribute__((address_space(1))) void*)g,
        (__attribute__((address_space(3))) void*)l, 16, 0, 0);
  }
}

#define MFMA_BLK(i0, j0, AF)                                                   \
  _Pragma("unroll")                                                            \
  for (int ii = 0; ii < 4; ++ii)                                               \
    _Pragma("unroll")                                                          \
    for (int jj = 0; jj < 2; ++jj)                                             \
      _Pragma("unroll")                                                        \
      for (int kk = 0; kk < 2; ++kk)                                           \
        acc[(i0) + ii][(j0) + jj] = __builtin_amdgcn_mfma_f32_16x16x32_bf16(   \
            AF[ii * 2 + kk], bb[jj * 2 + kk], acc[(i0) + ii][(j0) + jj], 0, 0, 0);

template <int NT, int LDA, int LDB>
__device__ __forceinline__ void gemm256(const u16* __restrict__ A_b,
                                        const u16* __restrict__ B_b,
                                        char* sm, f32x4 (&acc)[8][4])
{
  const int tid = threadIdx.x;
  const int w = tid >> 6, lane = tid & 63;
  const int wr = w >> 2, wc = w & 3;
  const int lrow = lane & 15, quad = lane >> 4;
  const int sx = ((lrow >> 2) & 1) << 5;
  const int cb0 = (quad * 16) ^ sx;
  const int cb1 = (64 + quad * 16) ^ sx;
  char* aRd = sm + wr * 16384;
  char* bRd = sm + 32768 + (wc >> 1) * 16384;
  const int bR0 = (wc & 1) * 64;

  short8 aL[8], aH[8], bb[4];

#define ST_A(p, h, t) stage_half(A_b + (size_t)((h) * 128) * LDA + (t) * 64,   \
                                 LDA * 2, sm + (p) * 65536 + (h) * 16384, w, lane)
#define ST_B(p, h, t) stage_half(B_b + (size_t)((h) * 128) * LDB + (t) * 64,   \
                                 LDB * 2, sm + (p) * 65536 + 32768 + (h) * 16384, w, lane)
#define RD8(base, R, cb) (*(const short8*)((base) + (R) * 128 + (cb)))

  // prologue: buf0 <- tile0 (all), buf1.A <- tile1
  ST_A(0, 0, 0); ST_A(0, 1, 0); ST_B(0, 0, 0); ST_B(0, 1, 0);
  ST_A(1, 0, 1); ST_A(1, 1, 1);
  VMCNT(4);          // buf0 fully landed (allow 2 newest halves in flight)
  BARRIER();

  for (int t0 = 0; t0 < NT; t0 += 2) {
    const int t1 = t0 + 1;
    const int t2 = (t0 + 2 < NT) ? t0 + 2 : NT - 1;  // clamped (dead-region) tail
    const int t3 = (t0 + 3 < NT) ? t0 + 3 : NT - 1;
#pragma unroll
    for (int p = 0; p < 2; ++p) {
      const char* aP = aRd + p * 65536;
      const char* bP = bRd + p * 65536;
      const int tB = p ? t2 : t1;   // B-half staged this half-iter
      const int tA = p ? t3 : t2;   // A-half staged this half-iter
      // ---- phase 1: quad(m-lo, n-lo); read aL + b01
#pragma unroll
      for (int i = 0; i < 4; ++i) {
        const int R = i * 16 + lrow;
        aL[i * 2]     = RD8(aP, R, cb0);
        aL[i * 2 + 1] = RD8(aP, R, cb1);
      }
#pragma unroll
      for (int j = 0; j < 2; ++j) {
        const int R = bR0 + j * 16 + lrow;
        bb[j * 2]     = RD8(bP, R, cb0);
        bb[j * 2 + 1] = RD8(bP, R, cb1);
      }
      ST_B(p ^ 1, 0, tB);
      BARRIER(); LGKM0();
      __builtin_amdgcn_s_setprio(1);
      MFMA_BLK(0, 0, aL);
      __builtin_amdgcn_s_setprio(0);
      BARRIER();
      // ---- phase 2: quad(m-hi, n-lo); read aH
#pragma unroll
      for (int i = 0; i < 4; ++i) {
        const int R = 64 + i * 16 + lrow;
        aH[i * 2]     = RD8(aP, R, cb0);
        aH[i * 2 + 1] = RD8(aP, R, cb1);
      }
      ST_B(p ^ 1, 1, tB);
      BARRIER(); LGKM0();
      __builtin_amdgcn_s_setprio(1);
      MFMA_BLK(4, 0, aH);
      __builtin_amdgcn_s_setprio(0);
      BARRIER();
      // ---- phase 3: quad(m-lo, n-hi); read b23
#pragma unroll
      for (int j = 0; j < 2; ++j) {
        const int R = bR0 + 32 + j * 16 + lrow;
        bb[j * 2]     = RD8(bP, R, cb0);
        bb[j * 2 + 1] = RD8(bP, R, cb1);
      }
      ST_A(p, 0, tA);
      BARRIER(); LGKM0();
      __builtin_amdgcn_s_setprio(1);
      MFMA_BLK(0, 2, aL);
      __builtin_amdgcn_s_setprio(0);
      BARRIER();
      // ---- phase 4: quad(m-hi, n-hi); no reads
      ST_A(p, 1, tA);
      BARRIER();
      __builtin_amdgcn_s_setprio(1);
      MFMA_BLK(4, 2, aH);
      __builtin_amdgcn_s_setprio(0);
      VMCNT(4);       // gate: other buffer fully landed before next 4 phases
      BARRIER();
    }
  }
#undef ST_A
#undef ST_B
#undef RD8
}

#define ACC_INIT                                                               \
  f32x4 acc[8][4];                                                             \
  _Pragma("unroll") for (int i = 0; i < 8; ++i)                                \
  _Pragma("unroll") for (int j = 0; j < 4; ++j) {                              \
    f32x4 z = {0.f, 0.f, 0.f, 0.f}; acc[i][j] = z; }

#define EPI_IDX                                                                \
  const int tid = threadIdx.x;                                                 \
  const int w = tid >> 6, lane = tid & 63;                                     \
  const int wr = w >> 2, wc = w & 3;                                           \
  const int lrow = lane & 15, quad = lane >> 4;                                \
  (void)w;

// ---------------------------------------------------------------------------
// projq: Y[M,1024] bf16 = A[M,1024] @ W[1024,1024]^T + bias   (q and k)
// ---------------------------------------------------------------------------
__global__ __launch_bounds__(512, 2)
void projq256_kernel(const u16* __restrict__ A, const u16* __restrict__ W,
                     const float* __restrict__ bias, u16* __restrict__ Y)
{
  __shared__ __align__(16) char sm[131072];
  const int m0 = blockIdx.y * 256, n0 = blockIdx.x * 256;
  ACC_INIT;
  gemm256<16, 1024, 1024>(A + (size_t)m0 * 1024, W + (size_t)n0 * 1024, sm, acc);
  EPI_IDX;
#pragma unroll
  for (int j = 0; j < 4; ++j) {
    const int gn = n0 + wc * 64 + j * 16 + lrow;
    const float bj = bias[gn];
#pragma unroll
    for (int i = 0; i < 8; ++i) {
      const int gm = m0 + wr * 128 + i * 16 + quad * 4;
#pragma unroll
      for (int r = 0; r < 4; ++r)
        Y[(size_t)(gm + r) * 1024 + gn] = bf16_rne(acc[i][j][r] + bj);
    }
  }
}

// ---------------------------------------------------------------------------
// projv: Vt[b][e][t] bf16 = (ctx @ Wv^T + bv) transposed, via LDS bounce.
// ---------------------------------------------------------------------------
__global__ __launch_bounds__(512, 2)
void projv256_kernel(const u16* __restrict__ A, const u16* __restrict__ W,
                     const float* __restrict__ bias, u16* __restrict__ Vt)
{
  __shared__ __align__(16) char sm[131072];
  const int m0 = blockIdx.y * 256, n0 = blockIdx.x * 256;
  const int bblk = m0 >> 11, t0g = m0 & 2047;
  ACC_INIT;
  gemm256<16, 1024, 1024>(A + (size_t)m0 * 1024, W + (size_t)n0 * 1024, sm, acc);
  EPI_IDX;
  VMCNT(0); BARRIER();   // drain in-flight stages before reusing LDS

  u16* T = (u16*)sm;     // chunk: 128 e-rows x 256 t, stride 264 u16
#pragma unroll
  for (int ch = 0; ch < 2; ++ch) {
    BARRIER();
    if ((wc >> 1) == ch) {
#pragma unroll
      for (int j = 0; j < 4; ++j) {
        const int e_loc = (wc & 1) * 64 + j * 16 + lrow;
        const float bj = bias[n0 + ch * 128 + e_loc];
#pragma unroll
        for (int i = 0; i < 8; ++i) {
          const int t_l = wr * 128 + i * 16 + quad * 4;
          uint2 pk;
          pk.x = pack2(acc[i][j][0] + bj, acc[i][j][1] + bj);
          pk.y = pack2(acc[i][j][2] + bj, acc[i][j][3] + bj);
          *(uint2*)&T[e_loc * 264 + t_l] = pk;
        }
      }
    }
    __syncthreads();
    {
      const int row = tid >> 2, part = tid & 3;
      u16* gd = Vt + ((size_t)(bblk * 1024 + n0 + ch * 128 + row)) * 2048 + t0g + part * 64;
      const u16* Tr = &T[row * 264 + part * 64];
#pragma unroll
      for (int k = 0; k < 8; ++k)
        *(uint4*)(gd + k * 8) = *(const uint4*)(Tr + k * 8);
    }
    __syncthreads();
  }
}

// ---------------------------------------------------------------------------
// score: S[b,s,t] fp16 = scale * (q[b] @ k[b]^T)
// ---------------------------------------------------------------------------
__global__ __launch_bounds__(512, 2)
void score256_kernel(const u16* __restrict__ qb, const u16* __restrict__ kb,
                     _Float16* __restrict__ S)
{
  __shared__ __align__(16) char sm[131072];
  const int b = blockIdx.z;
  const int m0 = blockIdx.y * 256, n0 = blockIdx.x * 256;
  ACC_INIT;
  gemm256<16, 1024, 1024>(qb + ((size_t)b * 2048 + m0) * 1024,
                          kb + ((size_t)b * 2048 + n0) * 1024, sm, acc);
  EPI_IDX;
  const float scale = 0.03125f;  // 1/sqrt(1024)
#pragma unroll
  for (int j = 0; j < 4; ++j) {
    const int gn = n0 + wc * 64 + j * 16 + lrow;
#pragma unroll
    for (int i = 0; i < 8; ++i) {
      const int gm = m0 + wr * 128 + i * 16 + quad * 4;
#pragma unroll
      for (int r = 0; r < 4; ++r)
        S[((size_t)b * 2048 + gm + r) * 2048 + gn] = (_Float16)(acc[i][j][r] * scale);
    }
  }
}

// ---------------------------------------------------------------------------
// softmax over S rows (fp16 in), writes P bf16 in place (same 4096B row).
// ---------------------------------------------------------------------------
__global__ __launch_bounds__(256)
void softmax_kernel(_Float16* __restrict__ S)
{
  const int row = blockIdx.x;
  const int tid = threadIdx.x;
  _Float16* Sr = S + (size_t)row * 2048;
  h4 ah = *(const h4*)(Sr + tid * 4);
  h4 bh = *(const h4*)(Sr + 1024 + tid * 4);
  float a0 = (float)ah.x, a1 = (float)ah.y, a2 = (float)ah.z, a3 = (float)ah.w;
  float b0 = (float)bh.x, b1 = (float)bh.y, b2 = (float)bh.z, b3 = (float)bh.w;

  float m = fmaxf(fmaxf(fmaxf(a0, a1), fmaxf(a2, a3)),
                  fmaxf(fmaxf(b0, b1), fmaxf(b2, b3)));
#pragma unroll
  for (int off = 32; off > 0; off >>= 1) m = fmaxf(m, __shfl_xor(m, off));

  __shared__ float red[4];
  const int wid = tid >> 6, lane = tid & 63;
  if (lane == 0) red[wid] = m;
  __syncthreads();
  m = fmaxf(fmaxf(red[0], red[1]), fmaxf(red[2], red[3]));

  float e0 = __expf(a0 - m), e1 = __expf(a1 - m), e2 = __expf(a2 - m), e3 = __expf(a3 - m);
  float e4 = __expf(b0 - m), e5 = __expf(b1 - m), e6 = __expf(b2 - m), e7 = __expf(b3 - m);
  float s = ((e0 + e1) + (e2 + e3)) + ((e4 + e5) + (e6 + e7));
#pragma unroll
  for (int off = 32; off > 0; off >>= 1) s += __shfl_xor(s, off);
  __syncthreads();
  if (lane == 0) red[wid] = s;
  __syncthreads();
  s = red[0] + red[1] + red[2] + red[3];
  float inv = 1.0f / s;

  u16* P = (u16*)S;
  size_t pb = (size_t)row * 2048;
  uint2 w0, w1;
  w0.x = pack2(e0 * inv, e1 * inv);
  w0.y = pack2(e2 * inv, e3 * inv);
  w1.x = pack2(e4 * inv, e5 * inv);
  w1.y = pack2(e6 * inv, e7 * inv);
  *(uint2*)&P[pb + tid * 4] = w0;
  *(uint2*)&P[pb + 1024 + tid * 4] = w1;
}

// ---------------------------------------------------------------------------
// pv: O[b,s,e] fp32 = P[b] @ Vt[b]^T   (P row stride 2048, Vt row stride 2048)
// ---------------------------------------------------------------------------
__global__ __launch_bounds__(512, 2)
void pv256_kernel(const u16* __restrict__ P, const u16* __restrict__ Vt,
                  float* __restrict__ O)
{
  __shared__ __align__(16) char sm[131072];
  const int b = blockIdx.z;
  const int m0 = blockIdx.y * 256, n0 = blockIdx.x * 256;
  ACC_INIT;
  gemm256<32, 2048, 2048>(P + ((size_t)b * 2048 + m0) * 2048,
                          Vt + ((size_t)b * 1024 + n0) * 2048, sm, acc);
  EPI_IDX;
#pragma unroll
  for (int j = 0; j < 4; ++j) {
    const int gn = n0 + wc * 64 + j * 16 + lrow;
#pragma unroll
    for (int i = 0; i < 8; ++i) {
      const int gm = m0 + wr * 128 + i * 16 + quad * 4;
#pragma unroll
      for (int r = 0; r < 4; ++r)
        O[((size_t)b * 2048 + gm + r) * 1024 + gn] = acc[i][j][r];
    }
  }
}

// ---------------------------------------------------------------------------
extern "C" void kernel_launch(void* const* d_in, const int* in_sizes, int n_in,
                              void* d_out, int out_size, void* d_ws, size_t ws_size,
                              hipStream_t stream) {
  const float* x   = (const float*)d_in[0];
  const float* ctx = (const float*)d_in[1];
  const float* Wq  = (const float*)d_in[2];
  const float* bq  = (const float*)d_in[3];
  const float* Wk  = (const float*)d_in[4];
  const float* bk  = (const float*)d_in[5];
  const float* Wv  = (const float*)d_in[6];
  const float* bv  = (const float*)d_in[7];
  float* out = (float*)d_out;

  // ws layout (u16 elems): [xb 16.8M][cb 16.8M][qb][kb][vt][wqb 1M][wkb][wvb]
  // S (fp16, 33.5M elems = 64 MiB) aliases [xb cb] (dead after proj).
  const size_t NQ = (size_t)16384 * 1024;   // 16.8M
  const size_t NW = (size_t)1024 * 1024;    // 1M
  const size_t needed = (5 * NQ + 3 * NW) * sizeof(u16);  // ~174 MiB
  if (ws_size < needed) return;

  u16* xb  = (u16*)d_ws;
  u16* cb  = xb + NQ;
  u16* qb  = cb + NQ;
  u16* kb  = qb + NQ;
  u16* vt  = kb + NQ;
  u16* wqb = vt + NQ;
  u16* wkb = wqb + NW;
  u16* wvb = wkb + NW;
  _Float16* S = (_Float16*)d_ws;  // aliases xb+cb after projections complete

  dim3 blk256(256, 1, 1);
  dim3 blk512(512, 1, 1);
  hipLaunchKernelGGL(convert_kernel, dim3(17920, 1, 1), blk256, 0, stream,
                     x, ctx, Wq, Wk, Wv, xb, cb, wqb, wkb, wvb);
  hipLaunchKernelGGL(projq256_kernel, dim3(4, 64, 1), blk512, 0, stream, xb, wqb, bq, qb);
  hipLaunchKernelGGL(projq256_kernel, dim3(4, 64, 1), blk512, 0, stream, cb, wkb, bk, kb);
  hipLaunchKernelGGL(projv256_kernel, dim3(4, 64, 1), blk512, 0, stream, cb, wvb, bv, vt);
  hipLaunchKernelGGL(score256_kernel, dim3(8, 8, 8), blk512, 0, stream, qb, kb, S);
  hipLaunchKernelGGL(softmax_kernel, dim3(16384, 1, 1), blk256, 0, stream, S);
  hipLaunchKernelGGL(pv256_kernel, dim3(4, 8, 8), blk512, 0, stream, (const u16*)S, vt, out);
}